// Round 1
// baseline (1873.112 us; speedup 1.0000x reference)
//
#include <hip/hip_runtime.h>
#include <stdint.h>

#define NSEQ 256
#define LSEQ 384
#define DM   256
#define DP   128
#define NH   8
#define DHD  32
#define NL   (NSEQ*LSEQ)   /* 98304 */
#define LL   (LSEQ*LSEQ)   /* 147456 */
#define SCALE 0.17677669529663687f

typedef unsigned short u16;

__device__ __forceinline__ float b2f(u16 s){
  union { uint32_t u; float f; } v; v.u = ((uint32_t)s)<<16; return v.f;
}
__device__ __forceinline__ u16 f2b(float f){
  union { float f; uint32_t u; } v; v.f = f;
  uint32_t u = v.u;
  return (u16)((u + 0x7FFFu + ((u>>16)&1u)) >> 16);
}
__device__ __forceinline__ float wsum(float x){
  #pragma unroll
  for(int o=32;o>0;o>>=1) x += __shfl_xor(x,o,64);
  return x;
}
__device__ __forceinline__ float wmax(float x){
  #pragma unroll
  for(int o=32;o>0;o>>=1) x = fmaxf(x, __shfl_xor(x,o,64));
  return x;
}

// ---------------- K1: LayerNorm(msa) -> bf16, wave per row ----------------
__global__ __launch_bounds__(256) void k_ln_msa(const float* __restrict__ msa,
    const float* __restrict__ g, const float* __restrict__ b, u16* __restrict__ out){
  int lane = threadIdx.x & 63;
  int64_t row = (int64_t)blockIdx.x*4 + (threadIdx.x>>6);
  const float4 x = *(const float4*)(msa + row*DM + lane*4);
  float s = x.x+x.y+x.z+x.w;
  float q = x.x*x.x+x.y*x.y+x.z*x.z+x.w*x.w;
  s = wsum(s); q = wsum(q);
  float mean = s*(1.0f/DM);
  float rstd = rsqrtf(q*(1.0f/DM) - mean*mean + 1e-5f);
  int c = lane*4;
  float4 gv = *(const float4*)(g+c);
  float4 bv = *(const float4*)(b+c);
  ushort4 o;
  o.x=f2b((x.x-mean)*rstd*gv.x+bv.x);
  o.y=f2b((x.y-mean)*rstd*gv.y+bv.y);
  o.z=f2b((x.z-mean)*rstd*gv.z+bv.z);
  o.w=f2b((x.w-mean)*rstd*gv.w+bv.w);
  *(ushort4*)(out + row*DM + c) = o;
}

// ---------------- K2: u[l,h,c] = sum_d sw_k_w[c,h*32+d] * swq[l,h,d] -------
// swq[l,h,d] = (tar[l,:] @ sw_q_w + sw_q_b)*scale ; tar = msa_n row (n=0,l)
__global__ __launch_bounds__(256) void k_u(const u16* __restrict__ msa_n,
    const float* __restrict__ sw_q_w, const float* __restrict__ sw_q_b,
    const float* __restrict__ sw_k_w, float* __restrict__ u){
  __shared__ float tar[DM];
  __shared__ float swq[DM];
  int l = blockIdx.x, t = threadIdx.x;
  tar[t] = b2f(msa_n[(int64_t)l*DM + t]);
  __syncthreads();
  float acc = sw_q_b[t];
  for(int c=0;c<DM;c++) acc += tar[c]*sw_q_w[c*DM + t];
  swq[t] = acc * SCALE;
  __syncthreads();
  float res[NH];
  #pragma unroll
  for(int h=0;h<NH;h++){
    float a = 0.f;
    #pragma unroll
    for(int d=0;d<DHD;d+=4){
      float4 w = *(const float4*)(sw_k_w + t*DM + h*DHD + d);
      a += w.x*swq[h*DHD+d] + w.y*swq[h*DHD+d+1] + w.z*swq[h*DHD+d+2] + w.w*swq[h*DHD+d+3];
    }
    res[h]=a;
  }
  #pragma unroll
  for(int h=0;h<NH;h++) u[((int64_t)l*NH + h)*DM + t] = res[h];
}

// ---------------- K3: sw_logits + softmax over n -> seq_weight[n,l,h] ------
__global__ __launch_bounds__(256) void k_seqw(const u16* __restrict__ msa_n,
    const float* __restrict__ u, float* __restrict__ sw){
  __shared__ float ul[NH*DM];
  __shared__ float lg[NH*256];
  __shared__ float mx[NH], sm[NH];
  int l = blockIdx.x, t = threadIdx.x;
  #pragma unroll
  for(int h=0;h<NH;h++) ul[h*DM+t] = u[((int64_t)l*NH+h)*DM + t];
  __syncthreads();
  float acc[NH] = {};
  const u16* row = msa_n + ((int64_t)t*LSEQ + l)*DM;   // n = t
  for(int c=0;c<DM;c+=4){
    ushort4 xv = *(const ushort4*)(row + c);
    float x0=b2f(xv.x), x1=b2f(xv.y), x2=b2f(xv.z), x3=b2f(xv.w);
    #pragma unroll
    for(int h=0;h<NH;h++)
      acc[h] += x0*ul[h*DM+c] + x1*ul[h*DM+c+1] + x2*ul[h*DM+c+2] + x3*ul[h*DM+c+3];
  }
  #pragma unroll
  for(int h=0;h<NH;h++) lg[h*256+t] = acc[h];
  __syncthreads();
  int wv = t>>6, ln = t&63;
  for(int h=wv; h<NH; h+=4){
    float a=lg[h*256+ln], b=lg[h*256+ln+64], c=lg[h*256+ln+128], d=lg[h*256+ln+192];
    float m = wmax(fmaxf(fmaxf(a,b),fmaxf(c,d)));
    float e = __expf(a-m)+__expf(b-m)+__expf(c-m)+__expf(d-m);
    e = wsum(e);
    if(ln==0){ mx[h]=m; sm[h]=1.f/e; }
  }
  __syncthreads();
  float o[NH];
  #pragma unroll
  for(int h=0;h<NH;h++) o[h] = __expf(acc[h]-mx[h])*sm[h];
  float* dst = sw + ((int64_t)t*LSEQ + l)*NH;
  *(float4*)dst     = make_float4(o[0],o[1],o[2],o[3]);
  *(float4*)(dst+4) = make_float4(o[4],o[5],o[6],o[7]);
}

// ---------------- K4: bias[h][q][k] = LN(pair[q,k,:]) @ wb -----------------
__global__ __launch_bounds__(256) void k_bias(const float* __restrict__ pair,
    const float* __restrict__ g, const float* __restrict__ b,
    const float* __restrict__ wb, float* __restrict__ bias){
  __shared__ float wbs[DP*NH];
  int t = threadIdx.x;
  #pragma unroll
  for(int i=0;i<4;i++) wbs[i*256+t] = wb[i*256+t];
  __syncthreads();
  int ln = t&63;
  int64_t row = (int64_t)blockIdx.x*4 + (t>>6);  // over L*L
  const float2 x = *(const float2*)(pair + row*DP + ln*2);
  float s = x.x+x.y, q = x.x*x.x+x.y*x.y;
  s = wsum(s); q = wsum(q);
  float mean = s*(1.f/DP);
  float rstd = rsqrtf(q*(1.f/DP)-mean*mean + 1e-5f);
  int c0 = ln*2;
  float y0 = (x.x-mean)*rstd*g[c0]+b[c0];
  float y1 = (x.y-mean)*rstd*g[c0+1]+b[c0+1];
  float p[NH];
  #pragma unroll
  for(int h=0;h<NH;h++) p[h] = y0*wbs[c0*NH+h] + y1*wbs[(c0+1)*NH+h];
  #pragma unroll
  for(int h=0;h<NH;h++) p[h] = wsum(p[h]);
  if(ln<NH) bias[(int64_t)ln*LL + row] = p[ln];
}

// ---------------- K5: projection GEMM (fp32 compute, bf16 A/out) -----------
// C[r][j] = sum_c A[r][c]*W[c][j]; modes: 0=q(*seq_weight) 1=k(*scale) 2=v 3=gate(sigmoid+bg)
__global__ __launch_bounds__(256) void k_proj(const u16* __restrict__ A,
    const float* __restrict__ W, u16* __restrict__ C,
    const float* __restrict__ aux, int mode){
  __shared__ float As[32][65];
  __shared__ float Bs[32][64];
  int t = threadIdx.x, tx = t&15, ty = t>>4;
  int cbase = blockIdx.x*64;
  int64_t rbase = (int64_t)blockIdx.y*64;
  float acc[4][4] = {};
  for(int k0=0;k0<DM;k0+=32){
    int arow = t>>2, ac = (t&3)*8;
    const u16* ap = A + (rbase+arow)*DM + k0 + ac;
    ushort4 a0 = *(const ushort4*)ap;
    ushort4 a1 = *(const ushort4*)(ap+4);
    As[ac+0][arow]=b2f(a0.x); As[ac+1][arow]=b2f(a0.y);
    As[ac+2][arow]=b2f(a0.z); As[ac+3][arow]=b2f(a0.w);
    As[ac+4][arow]=b2f(a1.x); As[ac+5][arow]=b2f(a1.y);
    As[ac+6][arow]=b2f(a1.z); As[ac+7][arow]=b2f(a1.w);
    int brow = t>>3, bc = (t&7)*8;
    const float* wp = W + (k0+brow)*DM + cbase + bc;
    *(float4*)&Bs[brow][bc]   = *(const float4*)wp;
    *(float4*)&Bs[brow][bc+4] = *(const float4*)(wp+4);
    __syncthreads();
    #pragma unroll
    for(int kk=0;kk<32;kk++){
      float av[4], bv[4];
      #pragma unroll
      for(int i=0;i<4;i++) av[i]=As[kk][ty*4+i];
      #pragma unroll
      for(int j=0;j<4;j++) bv[j]=Bs[kk][tx*4+j];
      #pragma unroll
      for(int i=0;i<4;i++)
        #pragma unroll
        for(int j=0;j<4;j++) acc[i][j] += av[i]*bv[j];
    }
    __syncthreads();
  }
  int col0 = cbase + tx*4;
  #pragma unroll
  for(int i=0;i<4;i++){
    int64_t r = rbase + ty*4 + i;
    float m0 = 1.f;
    if(mode==0) m0 = aux[r*NH + (col0>>5)];
    ushort4 o;
    u16 ov[4];
    #pragma unroll
    for(int j=0;j<4;j++){
      float v = acc[i][j];
      if(mode==0) v *= m0;
      else if(mode==1) v *= SCALE;
      else if(mode==3) v = 1.f/(1.f+__expf(-(v+aux[col0+j])));
      ov[j]=f2b(v);
    }
    o.x=ov[0]; o.y=ov[1]; o.z=ov[2]; o.w=ov[3];
    *(ushort4*)(C + r*DM + col0) = o;
  }
}

// ---------------- K6: scores[sc][h][q][k] partial over s-chunk -------------
__global__ __launch_bounds__(256) void k_scores(const u16* __restrict__ Q,
    const u16* __restrict__ K, float* __restrict__ scores){
  __shared__ float Qs[32][65];
  __shared__ float Ks[32][65];
  int qt = blockIdx.x, kt = blockIdx.y;
  int h = blockIdx.z>>2, sc = blockIdx.z&3;
  int t = threadIdx.x, tx=t&15, ty=t>>4;
  int row = t>>2, dc=(t&3)*8;
  float acc[4][4] = {};
  for(int s=sc*64; s<sc*64+64; s++){
    const u16* qp = Q + ((int64_t)s*LSEQ + qt*64 + row)*DM + h*DHD + dc;
    ushort4 q0=*(const ushort4*)qp, q1=*(const ushort4*)(qp+4);
    const u16* kp = K + ((int64_t)s*LSEQ + kt*64 + row)*DM + h*DHD + dc;
    ushort4 k0=*(const ushort4*)kp, k1=*(const ushort4*)(kp+4);
    Qs[dc+0][row]=b2f(q0.x); Qs[dc+1][row]=b2f(q0.y);
    Qs[dc+2][row]=b2f(q0.z); Qs[dc+3][row]=b2f(q0.w);
    Qs[dc+4][row]=b2f(q1.x); Qs[dc+5][row]=b2f(q1.y);
    Qs[dc+6][row]=b2f(q1.z); Qs[dc+7][row]=b2f(q1.w);
    Ks[dc+0][row]=b2f(k0.x); Ks[dc+1][row]=b2f(k0.y);
    Ks[dc+2][row]=b2f(k0.z); Ks[dc+3][row]=b2f(k0.w);
    Ks[dc+4][row]=b2f(k1.x); Ks[dc+5][row]=b2f(k1.y);
    Ks[dc+6][row]=b2f(k1.z); Ks[dc+7][row]=b2f(k1.w);
    __syncthreads();
    #pragma unroll
    for(int d=0;d<DHD;d++){
      float av[4], bv[4];
      #pragma unroll
      for(int i=0;i<4;i++) av[i]=Qs[d][ty*4+i];
      #pragma unroll
      for(int j=0;j<4;j++) bv[j]=Ks[d][tx*4+j];
      #pragma unroll
      for(int i=0;i<4;i++)
        #pragma unroll
        for(int j=0;j<4;j++) acc[i][j] += av[i]*bv[j];
    }
    __syncthreads();
  }
  float* dst = scores + (int64_t)sc*(NH*LL) + ((int64_t)h*LSEQ + qt*64)*LSEQ + (int64_t)kt*64;
  #pragma unroll
  for(int i=0;i<4;i++)
    *(float4*)(dst + (int64_t)(ty*4+i)*LSEQ + tx*4) =
        make_float4(acc[i][0],acc[i][1],acc[i][2],acc[i][3]);
}

// ---------------- K7: sum slabs + bias, softmax over k; P -> slab 0 --------
__global__ __launch_bounds__(128) void k_softmax(float* __restrict__ scores,
    const float* __restrict__ bias){
  int hq = blockIdx.x, t = threadIdx.x;
  int64_t base = (int64_t)hq*LSEQ;
  float v[3];
  #pragma unroll
  for(int i=0;i<3;i++){
    int k = t + i*128;
    float x = bias[base+k];
    x += scores[base+k];
    x += scores[(int64_t)1*NH*LL + base + k];
    x += scores[(int64_t)2*NH*LL + base + k];
    x += scores[(int64_t)3*NH*LL + base + k];
    v[i]=x;
  }
  __shared__ float red[2], red2[2];
  int wv=t>>6, ln=t&63;
  float m = fmaxf(fmaxf(v[0],v[1]),v[2]);
  m = wmax(m);
  if(ln==0) red[wv]=m;
  __syncthreads();
  m = fmaxf(red[0],red[1]);
  float e = __expf(v[0]-m)+__expf(v[1]-m)+__expf(v[2]-m);
  e = wsum(e);
  if(ln==0) red2[wv]=e;
  __syncthreads();
  float inv = 1.f/(red2[0]+red2[1]);
  #pragma unroll
  for(int i=0;i<3;i++) scores[base + t + i*128] = __expf(v[i]-m)*inv;
}

// ---------------- K8: attnout[s,q,h,d] = sum_k P[h,q,k]*V[s,k,h,d] ---------
__global__ __launch_bounds__(256) void k_pv(const float* __restrict__ P,
    const u16* __restrict__ V, u16* __restrict__ out){
  __shared__ float Ps[64][68];      // [k][q]
  __shared__ float Vs[2][64][34];   // [s2][k][d]
  int qt=blockIdx.x, sp=blockIdx.y, h=blockIdx.z;
  int t=threadIdx.x, tx=t&15, ty=t>>4;
  float acc[2][4][2] = {};
  for(int k0=0;k0<LSEQ;k0+=64){
    int prow = t&63, pc = (t>>6)*16;
    const float* pp = P + ((int64_t)h*LSEQ + qt*64 + prow)*LSEQ + k0 + pc;
    #pragma unroll
    for(int c=0;c<16;c+=4){
      float4 pv = *(const float4*)(pp + c);
      Ps[pc+c+0][prow]=pv.x; Ps[pc+c+1][prow]=pv.y;
      Ps[pc+c+2][prow]=pv.z; Ps[pc+c+3][prow]=pv.w;
    }
    int ss=t>>7, vrow=(t&127)>>1, vc=(t&1)*16;
    const u16* vp = V + ((int64_t)(sp*2+ss)*LSEQ + k0 + vrow)*DM + h*DHD + vc;
    #pragma unroll
    for(int c=0;c<16;c+=4){
      ushort4 vv = *(const ushort4*)(vp + c);
      Vs[ss][vrow][vc+c+0]=b2f(vv.x); Vs[ss][vrow][vc+c+1]=b2f(vv.y);
      Vs[ss][vrow][vc+c+2]=b2f(vv.z); Vs[ss][vrow][vc+c+3]=b2f(vv.w);
    }
    __syncthreads();
    #pragma unroll
    for(int kk=0;kk<64;kk++){
      float4 pv4 = *(const float4*)&Ps[kk][ty*4];
      float v0=Vs[0][kk][tx*2], v1=Vs[0][kk][tx*2+1];
      float w0=Vs[1][kk][tx*2], w1=Vs[1][kk][tx*2+1];
      acc[0][0][0]+=pv4.x*v0; acc[0][0][1]+=pv4.x*v1;
      acc[0][1][0]+=pv4.y*v0; acc[0][1][1]+=pv4.y*v1;
      acc[0][2][0]+=pv4.z*v0; acc[0][2][1]+=pv4.z*v1;
      acc[0][3][0]+=pv4.w*v0; acc[0][3][1]+=pv4.w*v1;
      acc[1][0][0]+=pv4.x*w0; acc[1][0][1]+=pv4.x*w1;
      acc[1][1][0]+=pv4.y*w0; acc[1][1][1]+=pv4.y*w1;
      acc[1][2][0]+=pv4.z*w0; acc[1][2][1]+=pv4.z*w1;
      acc[1][3][0]+=pv4.w*w0; acc[1][3][1]+=pv4.w*w1;
    }
    __syncthreads();
  }
  #pragma unroll
  for(int s2=0;s2<2;s2++)
    #pragma unroll
    for(int i=0;i<4;i++){
      ushort2 o; o.x=f2b(acc[s2][i][0]); o.y=f2b(acc[s2][i][1]);
      *(ushort2*)(out + ((int64_t)(sp*2+s2)*LSEQ + qt*64 + ty*4+i)*DM + h*DHD + tx*2) = o;
    }
}

// ---------------- K9: out = (gate .* attnout) @ wo + bo (fp32 out) ---------
__global__ __launch_bounds__(256) void k_final(const u16* __restrict__ G,
    const u16* __restrict__ AO, const float* __restrict__ WO,
    const float* __restrict__ bo, float* __restrict__ out){
  __shared__ float As[32][65];
  __shared__ float Bs[32][64];
  int t=threadIdx.x, tx=t&15, ty=t>>4;
  int cbase = blockIdx.x*64;
  int64_t rbase = (int64_t)blockIdx.y*64;
  float acc[4][4]={};
  for(int k0=0;k0<DM;k0+=32){
    int arow=t>>2, ac=(t&3)*8;
    int64_t aoff = (rbase+arow)*DM + k0 + ac;
    ushort4 g0=*(const ushort4*)(G+aoff), g1=*(const ushort4*)(G+aoff+4);
    ushort4 a0=*(const ushort4*)(AO+aoff), a1=*(const ushort4*)(AO+aoff+4);
    As[ac+0][arow]=b2f(g0.x)*b2f(a0.x); As[ac+1][arow]=b2f(g0.y)*b2f(a0.y);
    As[ac+2][arow]=b2f(g0.z)*b2f(a0.z); As[ac+3][arow]=b2f(g0.w)*b2f(a0.w);
    As[ac+4][arow]=b2f(g1.x)*b2f(a1.x); As[ac+5][arow]=b2f(g1.y)*b2f(a1.y);
    As[ac+6][arow]=b2f(g1.z)*b2f(a1.z); As[ac+7][arow]=b2f(g1.w)*b2f(a1.w);
    int brow=t>>3, bc=(t&7)*8;
    const float* wp = WO + (k0+brow)*DM + cbase + bc;
    *(float4*)&Bs[brow][bc]   = *(const float4*)wp;
    *(float4*)&Bs[brow][bc+4] = *(const float4*)(wp+4);
    __syncthreads();
    #pragma unroll
    for(int kk=0;kk<32;kk++){
      float av[4], bv[4];
      #pragma unroll
      for(int i=0;i<4;i++) av[i]=As[kk][ty*4+i];
      #pragma unroll
      for(int j=0;j<4;j++) bv[j]=Bs[kk][tx*4+j];
      #pragma unroll
      for(int i=0;i<4;i++)
        #pragma unroll
        for(int j=0;j<4;j++) acc[i][j] += av[i]*bv[j];
    }
    __syncthreads();
  }
  int col0=cbase+tx*4;
  float4 bv = *(const float4*)(bo+col0);
  #pragma unroll
  for(int i=0;i<4;i++){
    int64_t r=rbase+ty*4+i;
    *(float4*)(out + r*DM + col0) =
        make_float4(acc[i][0]+bv.x, acc[i][1]+bv.y, acc[i][2]+bv.z, acc[i][3]+bv.w);
  }
}

extern "C" void kernel_launch(void* const* d_in, const int* in_sizes, int n_in,
                              void* d_out, int out_size, void* d_ws, size_t ws_size,
                              hipStream_t stream){
  const float* msa    = (const float*)d_in[0];
  const float* pair   = (const float*)d_in[1];
  const float* lmg    = (const float*)d_in[2];
  const float* lmb    = (const float*)d_in[3];
  const float* lpg    = (const float*)d_in[4];
  const float* lpb    = (const float*)d_in[5];
  const float* sw_q_w = (const float*)d_in[6];
  const float* sw_q_b = (const float*)d_in[7];
  const float* sw_k_w = (const float*)d_in[8];
  // d_in[9] = sw_k_b: unused — its contribution is constant over n and
  // cancels in the softmax over n (seq_weight).
  const float* wq     = (const float*)d_in[10];
  const float* wk     = (const float*)d_in[11];
  const float* wv     = (const float*)d_in[12];
  const float* wb     = (const float*)d_in[13];
  const float* wg     = (const float*)d_in[14];
  const float* bg     = (const float*)d_in[15];
  const float* wo     = (const float*)d_in[16];
  const float* bo     = (const float*)d_in[17];
  float* out = (float*)d_out;

  // workspace layout (bf16 activations, fp32 small tensors) ~269 MB total
  u16* msa_n = (u16*)d_ws;
  u16* qb = msa_n + (int64_t)NL*DM;
  u16* kb = qb + (int64_t)NL*DM;
  u16* vb = kb + (int64_t)NL*DM;
  u16* gb = vb + (int64_t)NL*DM;
  float* u    = (float*)(gb + (int64_t)NL*DM);
  float* sw   = u + (int64_t)LSEQ*NH*DM;
  float* bias = sw + (int64_t)NSEQ*LSEQ*NH;
  float* scores = bias + (int64_t)NH*LL;   // 4 slabs of [NH][L][L]
  u16* attnout = msa_n;                    // reuse: msa_n dead after projections

  k_ln_msa<<<NL/4, 256, 0, stream>>>(msa, lmg, lmb, msa_n);
  k_u<<<LSEQ, 256, 0, stream>>>(msa_n, sw_q_w, sw_q_b, sw_k_w, u);
  k_seqw<<<LSEQ, 256, 0, stream>>>(msa_n, u, sw);
  k_bias<<<LL/4, 256, 0, stream>>>(pair, lpg, lpb, wb, bias);
  k_proj<<<dim3(4, NL/64), 256, 0, stream>>>(msa_n, wq, qb, sw, 0);
  k_proj<<<dim3(4, NL/64), 256, 0, stream>>>(msa_n, wk, kb, nullptr, 1);
  k_proj<<<dim3(4, NL/64), 256, 0, stream>>>(msa_n, wv, vb, nullptr, 2);
  k_proj<<<dim3(4, NL/64), 256, 0, stream>>>(msa_n, wg, gb, bg, 3);
  k_scores<<<dim3(6,6,32), 256, 0, stream>>>(qb, kb, scores);
  k_softmax<<<NH*LSEQ, 128, 0, stream>>>(scores, bias);
  k_pv<<<dim3(6,128,NH), 256, 0, stream>>>(scores, vb, attnout);
  k_final<<<dim3(4, NL/64), 256, 0, stream>>>(gb, attnout, wo, bo, out);
}

// Round 2
// 736.428 us; speedup vs baseline: 2.5435x; 2.5435x over previous
//
#include <hip/hip_runtime.h>
#include <stdint.h>

#define NSEQ 256
#define LSEQ 384
#define DM   256
#define DP   128
#define NH   8
#define DHD  32
#define NL   (NSEQ*LSEQ)   /* 98304 */
#define LL   (LSEQ*LSEQ)   /* 147456 */
#define SCALE 0.17677669529663687f

typedef unsigned short u16;
typedef short bf16x8 __attribute__((ext_vector_type(8)));
typedef float f32x4 __attribute__((ext_vector_type(4)));

__device__ __forceinline__ float b2f(u16 s){
  union { uint32_t u; float f; } v; v.u = ((uint32_t)s)<<16; return v.f;
}
__device__ __forceinline__ u16 f2b(float f){
  union { float f; uint32_t u; } v; v.f = f;
  uint32_t u = v.u;
  return (u16)((u + 0x7FFFu + ((u>>16)&1u)) >> 16);
}
__device__ __forceinline__ float wsum(float x){
  #pragma unroll
  for(int o=32;o>0;o>>=1) x += __shfl_xor(x,o,64);
  return x;
}
__device__ __forceinline__ float wmax(float x){
  #pragma unroll
  for(int o=32;o>0;o>>=1) x = fmaxf(x, __shfl_xor(x,o,64));
  return x;
}
// async 16B global->LDS. LDS dest = wave-uniform base + lane*16.
__device__ __forceinline__ void gload16(const void* g, void* l){
  __builtin_amdgcn_global_load_lds((const __attribute__((address_space(1))) void*)g,
      (__attribute__((address_space(3))) void*)l, 16, 0, 0);
}

// ---------------- K1: LayerNorm(msa) -> bf16, wave per row ----------------
__global__ __launch_bounds__(256) void k_ln_msa(const float* __restrict__ msa,
    const float* __restrict__ g, const float* __restrict__ b, u16* __restrict__ out){
  int lane = threadIdx.x & 63;
  int64_t row = (int64_t)blockIdx.x*4 + (threadIdx.x>>6);
  const float4 x = *(const float4*)(msa + row*DM + lane*4);
  float s = x.x+x.y+x.z+x.w;
  float q = x.x*x.x+x.y*x.y+x.z*x.z+x.w*x.w;
  s = wsum(s); q = wsum(q);
  float mean = s*(1.0f/DM);
  float rstd = rsqrtf(q*(1.0f/DM) - mean*mean + 1e-5f);
  int c = lane*4;
  float4 gv = *(const float4*)(g+c);
  float4 bv = *(const float4*)(b+c);
  ushort4 o;
  o.x=f2b((x.x-mean)*rstd*gv.x+bv.x);
  o.y=f2b((x.y-mean)*rstd*gv.y+bv.y);
  o.z=f2b((x.z-mean)*rstd*gv.z+bv.z);
  o.w=f2b((x.w-mean)*rstd*gv.w+bv.w);
  *(ushort4*)(out + row*DM + c) = o;
}

// ---------------- K2: weight convert+transpose fp32 -> bf16 ----------------
// z=0..3: WTall[n + z*256][k] = {wq,wk,wv,wg}[k][n] ; z=4: WOT[n][k]=wo[k][n]
__global__ __launch_bounds__(256) void k_wconv(const float* __restrict__ wq,
    const float* __restrict__ wk, const float* __restrict__ wv,
    const float* __restrict__ wg, const float* __restrict__ wo,
    u16* __restrict__ WTall, u16* __restrict__ WOT){
  __shared__ float tile[64][65];
  int z = blockIdx.z;
  const float* src = (z==0)?wq:(z==1)?wk:(z==2)?wv:(z==3)?wg:wo;
  u16* dst = (z<4) ? (WTall + z*DM*DM) : WOT;
  int k0 = blockIdx.x*64, n0 = blockIdx.y*64, t = threadIdx.x;
  int r = t>>4, c4 = (t&15)*4;
  #pragma unroll
  for(int it=0; it<4; it++){
    float4 v = *(const float4*)(src + (int64_t)(k0 + it*16 + r)*DM + n0 + c4);
    tile[it*16+r][c4+0]=v.x; tile[it*16+r][c4+1]=v.y;
    tile[it*16+r][c4+2]=v.z; tile[it*16+r][c4+3]=v.w;
  }
  __syncthreads();
  #pragma unroll
  for(int it=0; it<4; it++){
    int nl = it*16 + r, kl = c4;
    ushort4 o;
    o.x=f2b(tile[kl+0][nl]); o.y=f2b(tile[kl+1][nl]);
    o.z=f2b(tile[kl+2][nl]); o.w=f2b(tile[kl+3][nl]);
    *(ushort4*)(dst + (int64_t)(n0+nl)*DM + k0 + kl) = o;
  }
}

// ---------------- K3: u[l,h,c] = sum_d sw_k_w[c,h*32+d] * swq[l,h,d] -------
__global__ __launch_bounds__(256) void k_u(const u16* __restrict__ msa_n,
    const float* __restrict__ sw_q_w, const float* __restrict__ sw_q_b,
    const float* __restrict__ sw_k_w, float* __restrict__ u){
  __shared__ float tar[DM];
  __shared__ float swq[DM];
  int l = blockIdx.x, t = threadIdx.x;
  tar[t] = b2f(msa_n[(int64_t)l*DM + t]);
  __syncthreads();
  float acc = sw_q_b[t];
  for(int c=0;c<DM;c++) acc += tar[c]*sw_q_w[c*DM + t];
  swq[t] = acc * SCALE;
  __syncthreads();
  float res[NH];
  #pragma unroll
  for(int h=0;h<NH;h++){
    float a = 0.f;
    #pragma unroll
    for(int d=0;d<DHD;d+=4){
      float4 w = *(const float4*)(sw_k_w + t*DM + h*DHD + d);
      a += w.x*swq[h*DHD+d] + w.y*swq[h*DHD+d+1] + w.z*swq[h*DHD+d+2] + w.w*swq[h*DHD+d+3];
    }
    res[h]=a;
  }
  #pragma unroll
  for(int h=0;h<NH;h++) u[((int64_t)l*NH + h)*DM + t] = res[h];
}

// ---------------- K4: sw_logits + softmax over n -> seq_weight[n,l,h] ------
__global__ __launch_bounds__(256) void k_seqw(const u16* __restrict__ msa_n,
    const float* __restrict__ u, float* __restrict__ sw){
  __shared__ float ul[NH*DM];
  __shared__ float lg[NH*256];
  __shared__ float mx[NH], sm[NH];
  int l = blockIdx.x, t = threadIdx.x;
  #pragma unroll
  for(int h=0;h<NH;h++) ul[h*DM+t] = u[((int64_t)l*NH+h)*DM + t];
  __syncthreads();
  float acc[NH] = {};
  const u16* row = msa_n + ((int64_t)t*LSEQ + l)*DM;   // n = t
  for(int c=0;c<DM;c+=4){
    ushort4 xv = *(const ushort4*)(row + c);
    float x0=b2f(xv.x), x1=b2f(xv.y), x2=b2f(xv.z), x3=b2f(xv.w);
    #pragma unroll
    for(int h=0;h<NH;h++)
      acc[h] += x0*ul[h*DM+c] + x1*ul[h*DM+c+1] + x2*ul[h*DM+c+2] + x3*ul[h*DM+c+3];
  }
  #pragma unroll
  for(int h=0;h<NH;h++) lg[h*256+t] = acc[h];
  __syncthreads();
  int wv = t>>6, ln = t&63;
  for(int h=wv; h<NH; h+=4){
    float a=lg[h*256+ln], b=lg[h*256+ln+64], c=lg[h*256+ln+128], d=lg[h*256+ln+192];
    float m = wmax(fmaxf(fmaxf(a,b),fmaxf(c,d)));
    float e = __expf(a-m)+__expf(b-m)+__expf(c-m)+__expf(d-m);
    e = wsum(e);
    if(ln==0){ mx[h]=m; sm[h]=1.f/e; }
  }
  __syncthreads();
  float o[NH];
  #pragma unroll
  for(int h=0;h<NH;h++) o[h] = __expf(acc[h]-mx[h])*sm[h];
  float* dst = sw + ((int64_t)t*LSEQ + l)*NH;
  *(float4*)dst     = make_float4(o[0],o[1],o[2],o[3]);
  *(float4*)(dst+4) = make_float4(o[4],o[5],o[6],o[7]);
}

// ---------------- K5: bias[h][q][k] = LN(pair[q,k,:]) @ wb -----------------
__global__ __launch_bounds__(256) void k_bias(const float* __restrict__ pair,
    const float* __restrict__ g, const float* __restrict__ b,
    const float* __restrict__ wb, float* __restrict__ bias){
  __shared__ float wbs[DP*NH];
  int t = threadIdx.x;
  #pragma unroll
  for(int i=0;i<4;i++) wbs[i*256+t] = wb[i*256+t];
  __syncthreads();
  int ln = t&63;
  int64_t row = (int64_t)blockIdx.x*4 + (t>>6);  // over L*L
  const float2 x = *(const float2*)(pair + row*DP + ln*2);
  float s = x.x+x.y, q = x.x*x.x+x.y*x.y;
  s = wsum(s); q = wsum(q);
  float mean = s*(1.f/DP);
  float rstd = rsqrtf(q*(1.f/DP)-mean*mean + 1e-5f);
  int c0 = ln*2;
  float y0 = (x.x-mean)*rstd*g[c0]+b[c0];
  float y1 = (x.y-mean)*rstd*g[c0+1]+b[c0+1];
  float p[NH];
  #pragma unroll
  for(int h=0;h<NH;h++) p[h] = y0*wbs[c0*NH+h] + y1*wbs[(c0+1)*NH+h];
  #pragma unroll
  for(int h=0;h<NH;h++) p[h] = wsum(p[h]);
  if(ln<NH) bias[(int64_t)ln*LL + row] = p[ln];
}

// ==================== MFMA GEMM core (shared idioms) ========================
// 128x128 tile, 4 waves (2x2 of 64x64), BK=64, 16x16x32 bf16 MFMA.
// LDS rows: 64 bf16 = 8 chunks of 16B; logical chunk g stored at phys g^(row&7).

// ---------------- K6: fused projection C[98304][1024] = msa_n @ [wq|wk|wv|wg]
__global__ __launch_bounds__(256) void k_projf(const u16* __restrict__ A,
    const u16* __restrict__ WT, u16* __restrict__ qb, u16* __restrict__ kb,
    u16* __restrict__ gbuf, u16* __restrict__ VT,
    const float* __restrict__ sw, const float* __restrict__ bg){
  __shared__ short As[128*64];
  __shared__ short Bs[128*64];
  int t = threadIdx.x;
  int w = t>>6, lane = t&63, ln15 = lane&15, quad = lane>>4;
  int rIn = lane>>3, cch = lane&7;
  int mw = (w>>1)*64, nw = (w&1)*64;
  int bx = blockIdx.x;              // 0..7 -> col tile (mode = bx>>1)
  int by = blockIdx.y;              // 0..767 row tile
  int n0 = bx*128;
  int64_t r0 = (int64_t)by*128;
  int g = cch ^ rIn;                // swizzled logical chunk (const per lane)
  f32x4 acc[4][4] = {};
  for(int it=0; it<4; it++){
    int k0 = it*64;
    __syncthreads();
    #pragma unroll
    for(int ti=0; ti<4; ti++){
      int row = w*32 + ti*8 + rIn;
      gload16(A  + (r0+row)*DM + k0 + g*8, &As[(w*32+ti*8)*64]);
      gload16(WT + (int64_t)(n0+row)*DM + k0 + g*8, &Bs[(w*32+ti*8)*64]);
    }
    __syncthreads();
    #pragma unroll
    for(int kk=0;kk<2;kk++){
      int p = (kk*4+quad) ^ (lane&7);
      bf16x8 af[4], bfv[4];
      #pragma unroll
      for(int i=0;i<4;i++) af[i]  = *(const bf16x8*)&As[(mw+i*16+ln15)*64 + p*8];
      #pragma unroll
      for(int j=0;j<4;j++) bfv[j] = *(const bf16x8*)&Bs[(nw+j*16+ln15)*64 + p*8];
      #pragma unroll
      for(int i=0;i<4;i++)
        #pragma unroll
        for(int j=0;j<4;j++)
          acc[i][j] = __builtin_amdgcn_mfma_f32_16x16x32_bf16(af[i], bfv[j], acc[i][j], 0,0,0);
    }
  }
  int mode = bx>>1;
  int cmb = (bx&1)*128 + nw;        // within-mode col base for this wave
  if(mode==2){
    // V: write transposed VT[h][s][d][kpos], 4 regs = 4 consecutive kpos
    int s = by/3, kb3 = (by%3)*128 + mw;
    #pragma unroll
    for(int j=0;j<4;j++){
      int cm = cmb + j*16 + ln15;
      int hh = cm>>5, d = cm&31;
      #pragma unroll
      for(int i=0;i<4;i++){
        int kpos0 = kb3 + i*16 + quad*4;
        ushort4 o;
        o.x=f2b(acc[i][j][0]); o.y=f2b(acc[i][j][1]);
        o.z=f2b(acc[i][j][2]); o.w=f2b(acc[i][j][3]);
        *(ushort4*)(VT + ((int64_t)(hh*NSEQ+s)*DHD + d)*LSEQ + kpos0) = o;
      }
    }
  } else {
    u16* dst = (mode==0)?qb:(mode==1)?kb:gbuf;
    float bgv[4];
    if(mode==3){
      #pragma unroll
      for(int j=0;j<4;j++) bgv[j] = bg[cmb + j*16 + ln15];
    }
    #pragma unroll
    for(int i=0;i<4;i++)
      #pragma unroll
      for(int reg=0;reg<4;reg++){
        int64_t r = r0 + mw + i*16 + quad*4 + reg;
        #pragma unroll
        for(int j=0;j<4;j++){
          int cm = cmb + j*16 + ln15;
          float v = acc[i][j][reg];
          if(mode==0)      v *= sw[r*NH + (cm>>5)];
          else if(mode==1) v *= SCALE;
          else             v = 1.f/(1.f+__expf(-(v+bgv[j])));
          dst[r*DM + cm] = f2b(v);
        }
      }
  }
}

// ---------------- K7: scores slab sc: S[h][q][k] += Q.K over s-chunk -------
__global__ __launch_bounds__(256) void k_scores(const u16* __restrict__ Q,
    const u16* __restrict__ K, float* __restrict__ scores){
  __shared__ short As[128*64];
  __shared__ short Bs[128*64];
  int t = threadIdx.x;
  int w = t>>6, lane = t&63, ln15 = lane&15, quad = lane>>4;
  int rIn = lane>>3, cch = lane&7;
  int mw = (w>>1)*64, nw = (w&1)*64;
  int q0 = blockIdx.x*128, k0t = blockIdx.y*128;
  int h = blockIdx.z>>2, sc = blockIdx.z&3;
  int g = cch ^ rIn;
  int s_off = g>>2, d16 = g&3;
  f32x4 acc[4][4] = {};
  for(int i2=0; i2<32; i2++){
    int sb = sc*64 + i2*2 + s_off;
    __syncthreads();
    #pragma unroll
    for(int ti=0; ti<4; ti++){
      int row = w*32 + ti*8 + rIn;
      gload16(Q + ((int64_t)sb*LSEQ + q0 + row)*DM + h*DHD + d16*8, &As[(w*32+ti*8)*64]);
      gload16(K + ((int64_t)sb*LSEQ + k0t + row)*DM + h*DHD + d16*8, &Bs[(w*32+ti*8)*64]);
    }
    __syncthreads();
    #pragma unroll
    for(int kk=0;kk<2;kk++){
      int p = (kk*4+quad) ^ (lane&7);
      bf16x8 af[4], bfv[4];
      #pragma unroll
      for(int i=0;i<4;i++) af[i]  = *(const bf16x8*)&As[(mw+i*16+ln15)*64 + p*8];
      #pragma unroll
      for(int j=0;j<4;j++) bfv[j] = *(const bf16x8*)&Bs[(nw+j*16+ln15)*64 + p*8];
      #pragma unroll
      for(int i=0;i<4;i++)
        #pragma unroll
        for(int j=0;j<4;j++)
          acc[i][j] = __builtin_amdgcn_mfma_f32_16x16x32_bf16(af[i], bfv[j], acc[i][j], 0,0,0);
    }
  }
  int64_t slab = (int64_t)sc*NH*LL;
  #pragma unroll
  for(int i=0;i<4;i++)
    #pragma unroll
    for(int reg=0;reg<4;reg++){
      int q = q0 + mw + i*16 + quad*4 + reg;
      float* rp = scores + slab + ((int64_t)h*LSEQ + q)*LSEQ + k0t + nw + ln15;
      #pragma unroll
      for(int j=0;j<4;j++) rp[j*16] = acc[i][j][reg];
    }
}

// ---------------- K8: sum slabs + bias, softmax over k -> P bf16 -----------
__global__ __launch_bounds__(128) void k_softmax(const float* __restrict__ scores,
    const float* __restrict__ bias, u16* __restrict__ Pb){
  int hq = blockIdx.x, t = threadIdx.x;
  int64_t base = (int64_t)hq*LSEQ;
  float v[3];
  #pragma unroll
  for(int i=0;i<3;i++){
    int k = t + i*128;
    float x = bias[base+k];
    x += scores[base+k];
    x += scores[(int64_t)1*NH*LL + base + k];
    x += scores[(int64_t)2*NH*LL + base + k];
    x += scores[(int64_t)3*NH*LL + base + k];
    v[i]=x;
  }
  __shared__ float red[2], red2[2];
  int wv=t>>6, ln=t&63;
  float m = fmaxf(fmaxf(v[0],v[1]),v[2]);
  m = wmax(m);
  if(ln==0) red[wv]=m;
  __syncthreads();
  m = fmaxf(red[0],red[1]);
  float e = __expf(v[0]-m)+__expf(v[1]-m)+__expf(v[2]-m);
  e = wsum(e);
  if(ln==0) red2[wv]=e;
  __syncthreads();
  float inv = 1.f/(red2[0]+red2[1]);
  #pragma unroll
  for(int i=0;i<3;i++) Pb[base + t + i*128] = f2b(__expf(v[i]-m)*inv);
}

// ---------------- K9: PV. C[(s,d)][q] = sum_k VT[h][(s,d)][k] * P[h][q][k] --
// epilogue: *gate, write attnout natural layout (ushort4 along d)
__global__ __launch_bounds__(256) void k_pv(const u16* __restrict__ VT,
    const u16* __restrict__ Pb, const u16* __restrict__ gbuf,
    u16* __restrict__ attn){
  __shared__ short As[128*64];
  __shared__ short Bs[128*64];
  int t = threadIdx.x;
  int w = t>>6, lane = t&63, ln15 = lane&15, quad = lane>>4;
  int rIn = lane>>3, cch = lane&7;
  int mw = (w>>1)*64, nw = (w&1)*64;
  int mx = blockIdx.x, ny = blockIdx.y, h = blockIdx.z;
  int g = cch ^ rIn;
  f32x4 acc[4][4] = {};
  for(int it=0; it<6; it++){
    int k0 = it*64;
    __syncthreads();
    #pragma unroll
    for(int ti=0; ti<4; ti++){
      int row = w*32 + ti*8 + rIn;
      gload16(VT + ((int64_t)h*8192 + mx*128 + row)*LSEQ + k0 + g*8, &As[(w*32+ti*8)*64]);
      gload16(Pb + ((int64_t)h*LSEQ + ny*128 + row)*LSEQ + k0 + g*8, &Bs[(w*32+ti*8)*64]);
    }
    __syncthreads();
    #pragma unroll
    for(int kk=0;kk<2;kk++){
      int p = (kk*4+quad) ^ (lane&7);
      bf16x8 af[4], bfv[4];
      #pragma unroll
      for(int i=0;i<4;i++) af[i]  = *(const bf16x8*)&As[(mw+i*16+ln15)*64 + p*8];
      #pragma unroll
      for(int j=0;j<4;j++) bfv[j] = *(const bf16x8*)&Bs[(nw+j*16+ln15)*64 + p*8];
      #pragma unroll
      for(int i=0;i<4;i++)
        #pragma unroll
        for(int j=0;j<4;j++)
          acc[i][j] = __builtin_amdgcn_mfma_f32_16x16x32_bf16(af[i], bfv[j], acc[i][j], 0,0,0);
    }
  }
  #pragma unroll
  for(int i=0;i<4;i++){
    int m0 = mx*128 + mw + i*16 + quad*4;
    int s = m0>>5, d0 = m0&31;
    #pragma unroll
    for(int j=0;j<4;j++){
      int q = ny*128 + nw + j*16 + ln15;
      int64_t base = ((int64_t)s*LSEQ + q)*DM + h*DHD + d0;
      ushort4 gv = *(const ushort4*)(gbuf + base);
      ushort4 o;
      o.x = f2b(acc[i][j][0]*b2f(gv.x));
      o.y = f2b(acc[i][j][1]*b2f(gv.y));
      o.z = f2b(acc[i][j][2]*b2f(gv.z));
      o.w = f2b(acc[i][j][3]*b2f(gv.w));
      *(ushort4*)(attn + base) = o;
    }
  }
}

// ---------------- K10: out = attnout @ wo + bo (fp32 out) ------------------
__global__ __launch_bounds__(256) void k_final(const u16* __restrict__ A,
    const u16* __restrict__ WOT, const float* __restrict__ bo,
    float* __restrict__ out){
  __shared__ short As[128*64];
  __shared__ short Bs[128*64];
  int t = threadIdx.x;
  int w = t>>6, lane = t&63, ln15 = lane&15, quad = lane>>4;
  int rIn = lane>>3, cch = lane&7;
  int mw = (w>>1)*64, nw = (w&1)*64;
  int n0 = blockIdx.x*128;
  int64_t r0 = (int64_t)blockIdx.y*128;
  int g = cch ^ rIn;
  f32x4 acc[4][4] = {};
  for(int it=0; it<4; it++){
    int k0 = it*64;
    __syncthreads();
    #pragma unroll
    for(int ti=0; ti<4; ti++){
      int row = w*32 + ti*8 + rIn;
      gload16(A   + (r0+row)*DM + k0 + g*8, &As[(w*32+ti*8)*64]);
      gload16(WOT + (int64_t)(n0+row)*DM + k0 + g*8, &Bs[(w*32+ti*8)*64]);
    }
    __syncthreads();
    #pragma unroll
    for(int kk=0;kk<2;kk++){
      int p = (kk*4+quad) ^ (lane&7);
      bf16x8 af[4], bfv[4];
      #pragma unroll
      for(int i=0;i<4;i++) af[i]  = *(const bf16x8*)&As[(mw+i*16+ln15)*64 + p*8];
      #pragma unroll
      for(int j=0;j<4;j++) bfv[j] = *(const bf16x8*)&Bs[(nw+j*16+ln15)*64 + p*8];
      #pragma unroll
      for(int i=0;i<4;i++)
        #pragma unroll
        for(int j=0;j<4;j++)
          acc[i][j] = __builtin_amdgcn_mfma_f32_16x16x32_bf16(af[i], bfv[j], acc[i][j], 0,0,0);
    }
  }
  float bv[4];
  #pragma unroll
  for(int j=0;j<4;j++) bv[j] = bo[n0 + nw + j*16 + ln15];
  #pragma unroll
  for(int i=0;i<4;i++)
    #pragma unroll
    for(int reg=0;reg<4;reg++){
      int64_t r = r0 + mw + i*16 + quad*4 + reg;
      float* rp = out + r*DM + n0 + nw + ln15;
      #pragma unroll
      for(int j=0;j<4;j++) rp[j*16] = acc[i][j][reg] + bv[j];
    }
}

extern "C" void kernel_launch(void* const* d_in, const int* in_sizes, int n_in,
                              void* d_out, int out_size, void* d_ws, size_t ws_size,
                              hipStream_t stream){
  const float* msa    = (const float*)d_in[0];
  const float* pair   = (const float*)d_in[1];
  const float* lmg    = (const float*)d_in[2];
  const float* lmb    = (const float*)d_in[3];
  const float* lpg    = (const float*)d_in[4];
  const float* lpb    = (const float*)d_in[5];
  const float* sw_q_w = (const float*)d_in[6];
  const float* sw_q_b = (const float*)d_in[7];
  const float* sw_k_w = (const float*)d_in[8];
  // d_in[9] = sw_k_b: constant over n, cancels in softmax over n.
  const float* wq     = (const float*)d_in[10];
  const float* wk     = (const float*)d_in[11];
  const float* wv     = (const float*)d_in[12];
  const float* wb     = (const float*)d_in[13];
  const float* wg     = (const float*)d_in[14];
  const float* bg     = (const float*)d_in[15];
  const float* wo     = (const float*)d_in[16];
  const float* bo     = (const float*)d_in[17];
  float* out = (float*)d_out;

  // workspace layout (~285 MB)
  u16* msa_n = (u16*)d_ws;                       // [NL][256] bf16
  u16* qb    = msa_n + (int64_t)NL*DM;
  u16* kb    = qb + (int64_t)NL*DM;
  u16* gbuf  = kb + (int64_t)NL*DM;
  u16* VT    = gbuf + (int64_t)NL*DM;            // [8][256][32][384] bf16
  u16* Pb    = VT + (int64_t)NL*DM;              // [8][384][384] bf16
  u16* WTall = Pb + (int64_t)NH*LSEQ*LSEQ;       // [1024][256] bf16
  u16* WOT   = WTall + 1024*DM;                  // [256][256] bf16
  float* u_buf = (float*)(WOT + DM*DM);          // [384][8][256] f32
  float* sw  = u_buf + (int64_t)LSEQ*NH*DM;      // [256*384][8] f32
  float* bias = sw + (int64_t)NL*NH;             // [8][384][384] f32
  float* scores = bias + (int64_t)NH*LL;         // 4 slabs [8][384][384] f32
  u16* attnout = msa_n;                          // alias: msa_n dead after proj

  k_ln_msa<<<NL/4, 256, 0, stream>>>(msa, lmg, lmb, msa_n);
  k_wconv<<<dim3(4,4,5), 256, 0, stream>>>(wq, wk, wv, wg, wo, WTall, WOT);
  k_u<<<LSEQ, 256, 0, stream>>>(msa_n, sw_q_w, sw_q_b, sw_k_w, u_buf);
  k_seqw<<<LSEQ, 256, 0, stream>>>(msa_n, u_buf, sw);
  k_bias<<<LL/4, 256, 0, stream>>>(pair, lpg, lpb, wb, bias);
  k_projf<<<dim3(8, NL/128), 256, 0, stream>>>(msa_n, WTall, qb, kb, gbuf, VT, sw, bg);
  k_scores<<<dim3(3,3,32), 256, 0, stream>>>(qb, kb, scores);
  k_softmax<<<NH*LSEQ, 128, 0, stream>>>(scores, bias, Pb);
  k_pv<<<dim3(64,3,NH), 256, 0, stream>>>(VT, Pb, gbuf, attnout);
  k_final<<<dim3(2, NL/128), 256, 0, stream>>>(attnout, WOT, bo, out);
}

// Round 3
// 728.277 us; speedup vs baseline: 2.5720x; 1.0112x over previous
//
#include <hip/hip_runtime.h>
#include <hip/hip_fp16.h>
#include <stdint.h>

#define NSEQ 256
#define LSEQ 384
#define DM   256
#define DP   128
#define NH   8
#define DHD  32
#define NL   (NSEQ*LSEQ)   /* 98304 */
#define LL   (LSEQ*LSEQ)   /* 147456 */
#define SCALE 0.17677669529663687f

typedef unsigned short u16;
typedef short bf16x8 __attribute__((ext_vector_type(8)));
typedef float f32x4 __attribute__((ext_vector_type(4)));

__device__ __forceinline__ float b2f(u16 s){
  union { uint32_t u; float f; } v; v.u = ((uint32_t)s)<<16; return v.f;
}
__device__ __forceinline__ u16 f2b(float f){
  union { float f; uint32_t u; } v; v.f = f;
  uint32_t u = v.u;
  return (u16)((u + 0x7FFFu + ((u>>16)&1u)) >> 16);
}
__device__ __forceinline__ float wsum(float x){
  #pragma unroll
  for(int o=32;o>0;o>>=1) x += __shfl_xor(x,o,64);
  return x;
}
__device__ __forceinline__ float wmax(float x){
  #pragma unroll
  for(int o=32;o>0;o>>=1) x = fmaxf(x, __shfl_xor(x,o,64));
  return x;
}
// async 16B global->LDS. LDS dest = wave-uniform base + lane*16.
__device__ __forceinline__ void gload16(const void* g, void* l){
  __builtin_amdgcn_global_load_lds((const __attribute__((address_space(1))) void*)g,
      (__attribute__((address_space(3))) void*)l, 16, 0, 0);
}

// ---------------- K1: LayerNorm(msa) -> bf16, wave per row ----------------
__global__ __launch_bounds__(256) void k_ln_msa(const float* __restrict__ msa,
    const float* __restrict__ g, const float* __restrict__ b, u16* __restrict__ out){
  int lane = threadIdx.x & 63;
  int64_t row = (int64_t)blockIdx.x*4 + (threadIdx.x>>6);
  const float4 x = *(const float4*)(msa + row*DM + lane*4);
  float s = x.x+x.y+x.z+x.w;
  float q = x.x*x.x+x.y*x.y+x.z*x.z+x.w*x.w;
  s = wsum(s); q = wsum(q);
  float mean = s*(1.0f/DM);
  float rstd = rsqrtf(q*(1.0f/DM) - mean*mean + 1e-5f);
  int c = lane*4;
  float4 gv = *(const float4*)(g+c);
  float4 bv = *(const float4*)(b+c);
  ushort4 o;
  o.x=f2b((x.x-mean)*rstd*gv.x+bv.x);
  o.y=f2b((x.y-mean)*rstd*gv.y+bv.y);
  o.z=f2b((x.z-mean)*rstd*gv.z+bv.z);
  o.w=f2b((x.w-mean)*rstd*gv.w+bv.w);
  *(ushort4*)(out + row*DM + c) = o;
}

// ---------------- K2: weight convert+transpose fp32 -> bf16 ----------------
__global__ __launch_bounds__(256) void k_wconv(const float* __restrict__ wq,
    const float* __restrict__ wk, const float* __restrict__ wv,
    const float* __restrict__ wg, const float* __restrict__ wo,
    u16* __restrict__ WTall, u16* __restrict__ WOT){
  __shared__ float tile[64][65];
  int z = blockIdx.z;
  const float* src = (z==0)?wq:(z==1)?wk:(z==2)?wv:(z==3)?wg:wo;
  u16* dst = (z<4) ? (WTall + z*DM*DM) : WOT;
  int k0 = blockIdx.x*64, n0 = blockIdx.y*64, t = threadIdx.x;
  int r = t>>4, c4 = (t&15)*4;
  #pragma unroll
  for(int it=0; it<4; it++){
    float4 v = *(const float4*)(src + (int64_t)(k0 + it*16 + r)*DM + n0 + c4);
    tile[it*16+r][c4+0]=v.x; tile[it*16+r][c4+1]=v.y;
    tile[it*16+r][c4+2]=v.z; tile[it*16+r][c4+3]=v.w;
  }
  __syncthreads();
  #pragma unroll
  for(int it=0; it<4; it++){
    int nl = it*16 + r, kl = c4;
    ushort4 o;
    o.x=f2b(tile[kl+0][nl]); o.y=f2b(tile[kl+1][nl]);
    o.z=f2b(tile[kl+2][nl]); o.w=f2b(tile[kl+3][nl]);
    *(ushort4*)(dst + (int64_t)(n0+nl)*DM + k0 + kl) = o;
  }
}

// ---------------- K3: u[l,h,c] = sum_d sw_k_w[c,h*32+d] * swq[l,h,d] -------
__global__ __launch_bounds__(256) void k_u(const u16* __restrict__ msa_n,
    const float* __restrict__ sw_q_w, const float* __restrict__ sw_q_b,
    const float* __restrict__ sw_k_w, float* __restrict__ u){
  __shared__ float tar[DM];
  __shared__ float swq[DM];
  int l = blockIdx.x, t = threadIdx.x;
  tar[t] = b2f(msa_n[(int64_t)l*DM + t]);
  __syncthreads();
  float acc = sw_q_b[t];
  for(int c=0;c<DM;c++) acc += tar[c]*sw_q_w[c*DM + t];
  swq[t] = acc * SCALE;
  __syncthreads();
  float res[NH];
  #pragma unroll
  for(int h=0;h<NH;h++){
    float a = 0.f;
    #pragma unroll
    for(int d=0;d<DHD;d+=4){
      float4 w = *(const float4*)(sw_k_w + t*DM + h*DHD + d);
      a += w.x*swq[h*DHD+d] + w.y*swq[h*DHD+d+1] + w.z*swq[h*DHD+d+2] + w.w*swq[h*DHD+d+3];
    }
    res[h]=a;
  }
  #pragma unroll
  for(int h=0;h<NH;h++) u[((int64_t)l*NH + h)*DM + t] = res[h];
}

// ---------------- K4: sw_logits + softmax over n -> seq_weight[n,l,h] ------
__global__ __launch_bounds__(256) void k_seqw(const u16* __restrict__ msa_n,
    const float* __restrict__ u, float* __restrict__ sw){
  __shared__ float ul[NH*DM];
  __shared__ float lg[NH*256];
  __shared__ float mx[NH], sm[NH];
  int l = blockIdx.x, t = threadIdx.x;
  #pragma unroll
  for(int h=0;h<NH;h++) ul[h*DM+t] = u[((int64_t)l*NH+h)*DM + t];
  __syncthreads();
  float acc[NH] = {};
  const u16* row = msa_n + ((int64_t)t*LSEQ + l)*DM;   // n = t
  for(int c=0;c<DM;c+=4){
    ushort4 xv = *(const ushort4*)(row + c);
    float x0=b2f(xv.x), x1=b2f(xv.y), x2=b2f(xv.z), x3=b2f(xv.w);
    #pragma unroll
    for(int h=0;h<NH;h++)
      acc[h] += x0*ul[h*DM+c] + x1*ul[h*DM+c+1] + x2*ul[h*DM+c+2] + x3*ul[h*DM+c+3];
  }
  #pragma unroll
  for(int h=0;h<NH;h++) lg[h*256+t] = acc[h];
  __syncthreads();
  int wv = t>>6, ln = t&63;
  for(int h=wv; h<NH; h+=4){
    float a=lg[h*256+ln], b=lg[h*256+ln+64], c=lg[h*256+ln+128], d=lg[h*256+ln+192];
    float m = wmax(fmaxf(fmaxf(a,b),fmaxf(c,d)));
    float e = __expf(a-m)+__expf(b-m)+__expf(c-m)+__expf(d-m);
    e = wsum(e);
    if(ln==0){ mx[h]=m; sm[h]=1.f/e; }
  }
  __syncthreads();
  float o[NH];
  #pragma unroll
  for(int h=0;h<NH;h++) o[h] = __expf(acc[h]-mx[h])*sm[h];
  float* dst = sw + ((int64_t)t*LSEQ + l)*NH;
  *(float4*)dst     = make_float4(o[0],o[1],o[2],o[3]);
  *(float4*)(dst+4) = make_float4(o[4],o[5],o[6],o[7]);
}

// ---------------- K5: bias[h][q][k] = LN(pair[q,k,:]) @ wb -----------------
// thread-per-row: serial LN stats + fp16-packed row in registers; all
// g/b/wb accesses are wave-uniform -> scalarized by compiler.
__global__ __launch_bounds__(256) void k_bias(const float* __restrict__ pair,
    const float* __restrict__ g, const float* __restrict__ b,
    const float* __restrict__ wb, float* __restrict__ bias){
  int64_t row = (int64_t)blockIdx.x*256 + threadIdx.x;   // over L*L
  const float* pr = pair + row*DP;
  uint2 xs[32];                       // 128 channels as packed fp16
  float s = 0.f, q = 0.f;
  #pragma unroll
  for(int i=0;i<32;i++){
    float4 v = *(const float4*)(pr + i*4);
    s += v.x+v.y+v.z+v.w;
    q += v.x*v.x+v.y*v.y+v.z*v.z+v.w*v.w;
    __half2 p0 = __floats2half2_rn(v.x, v.y);
    __half2 p1 = __floats2half2_rn(v.z, v.w);
    xs[i].x = *(const uint32_t*)&p0;
    xs[i].y = *(const uint32_t*)&p1;
  }
  float mean = s*(1.f/DP);
  float rstd = rsqrtf(q*(1.f/DP) - mean*mean + 1e-5f);
  float acc[NH] = {};
  #pragma unroll
  for(int i=0;i<32;i++){
    __half2 p0 = *(const __half2*)&xs[i].x;
    __half2 p1 = *(const __half2*)&xs[i].y;
    float2 f0 = __half22float2(p0);
    float2 f1 = __half22float2(p1);
    float xv[4] = {f0.x, f0.y, f1.x, f1.y};
    #pragma unroll
    for(int c4=0;c4<4;c4++){
      int c = i*4 + c4;
      float y = (xv[c4]-mean)*rstd*g[c] + b[c];
      #pragma unroll
      for(int h=0;h<NH;h++) acc[h] += y*wb[c*NH+h];
    }
  }
  #pragma unroll
  for(int h=0;h<NH;h++) bias[(int64_t)h*LL + row] = acc[h];
}

// ==================== MFMA GEMM core (shared idioms) ========================
// 128x128 tile, 4 waves (2x2 of 64x64), BK=64, 16x16x32 bf16 MFMA.
// LDS rows: 64 bf16 = 8 chunks of 16B; logical chunk g stored at phys g^(row&7).

// ---------------- K6: fused projection, one block per 128-row strip --------
// Loops all 8 col-tiles (q|k|v|g x2) so the A-tile is re-read from L2, not HBM.
__global__ __launch_bounds__(256) void k_projf(const u16* __restrict__ A,
    const u16* __restrict__ WT, u16* __restrict__ qb, u16* __restrict__ kb,
    u16* __restrict__ gbuf, u16* __restrict__ VT,
    const float* __restrict__ sw, const float* __restrict__ bg){
  __shared__ short As[128*64];
  __shared__ short Bs[128*64];
  int t = threadIdx.x;
  int w = t>>6, lane = t&63, ln15 = lane&15, quad = lane>>4;
  int rIn = lane>>3, cch = lane&7;
  int mw = (w>>1)*64, nw = (w&1)*64;
  int bx = blockIdx.x;              // 0..767 row tile
  int64_t r0 = (int64_t)bx*128;
  int g = cch ^ rIn;                // swizzled logical chunk (const per lane)
  for(int nt=0; nt<8; nt++){
    int n0 = nt*128;
    f32x4 acc[4][4] = {};
    for(int it=0; it<4; it++){
      int k0 = it*64;
      __syncthreads();
      #pragma unroll
      for(int ti=0; ti<4; ti++){
        int row = w*32 + ti*8 + rIn;
        gload16(A  + (r0+row)*DM + k0 + g*8, &As[(w*32+ti*8)*64]);
        gload16(WT + (int64_t)(n0+row)*DM + k0 + g*8, &Bs[(w*32+ti*8)*64]);
      }
      __syncthreads();
      #pragma unroll
      for(int kk=0;kk<2;kk++){
        int p = (kk*4+quad) ^ (lane&7);
        bf16x8 af[4], bfv[4];
        #pragma unroll
        for(int i=0;i<4;i++) af[i]  = *(const bf16x8*)&As[(mw+i*16+ln15)*64 + p*8];
        #pragma unroll
        for(int j=0;j<4;j++) bfv[j] = *(const bf16x8*)&Bs[(nw+j*16+ln15)*64 + p*8];
        #pragma unroll
        for(int i=0;i<4;i++)
          #pragma unroll
          for(int j=0;j<4;j++)
            acc[i][j] = __builtin_amdgcn_mfma_f32_16x16x32_bf16(af[i], bfv[j], acc[i][j], 0,0,0);
      }
    }
    int mode = nt>>1;
    int cmb = (nt&1)*128 + nw;      // within-mode col base for this wave
    if(mode==2){
      // V: write transposed VT[h][s][d][kpos], 4 regs = 4 consecutive kpos
      int s = bx/3, kb3 = (bx%3)*128 + mw;
      #pragma unroll
      for(int j=0;j<4;j++){
        int cm = cmb + j*16 + ln15;
        int hh = cm>>5, d = cm&31;
        #pragma unroll
        for(int i=0;i<4;i++){
          int kpos0 = kb3 + i*16 + quad*4;
          ushort4 o;
          o.x=f2b(acc[i][j][0]); o.y=f2b(acc[i][j][1]);
          o.z=f2b(acc[i][j][2]); o.w=f2b(acc[i][j][3]);
          *(ushort4*)(VT + ((int64_t)(hh*NSEQ+s)*DHD + d)*LSEQ + kpos0) = o;
        }
      }
    } else {
      u16* dst = (mode==0)?qb:(mode==1)?kb:gbuf;
      float bgv[4];
      if(mode==3){
        #pragma unroll
        for(int j=0;j<4;j++) bgv[j] = bg[cmb + j*16 + ln15];
      }
      #pragma unroll
      for(int i=0;i<4;i++)
        #pragma unroll
        for(int reg=0;reg<4;reg++){
          int64_t r = r0 + mw + i*16 + quad*4 + reg;
          #pragma unroll
          for(int j=0;j<4;j++){
            int cm = cmb + j*16 + ln15;
            float v = acc[i][j][reg];
            if(mode==0)      v *= sw[r*NH + (cm>>5)];
            else if(mode==1) v *= SCALE;
            else             v = 1.f/(1.f+__expf(-(v+bgv[j])));
            dst[r*DM + cm] = f2b(v);
          }
        }
    }
  }
}

// ---------------- K7: scores slab sc: S[h][q][k] += Q.K over s-chunk -------
__global__ __launch_bounds__(256) void k_scores(const u16* __restrict__ Q,
    const u16* __restrict__ K, float* __restrict__ scores){
  __shared__ short As[128*64];
  __shared__ short Bs[128*64];
  int t = threadIdx.x;
  int w = t>>6, lane = t&63, ln15 = lane&15, quad = lane>>4;
  int rIn = lane>>3, cch = lane&7;
  int mw = (w>>1)*64, nw = (w&1)*64;
  int q0 = blockIdx.x*128, k0t = blockIdx.y*128;
  int h = blockIdx.z>>2, sc = blockIdx.z&3;
  int g = cch ^ rIn;
  int s_off = g>>2, d16 = g&3;
  f32x4 acc[4][4] = {};
  for(int i2=0; i2<32; i2++){
    int sb = sc*64 + i2*2 + s_off;
    __syncthreads();
    #pragma unroll
    for(int ti=0; ti<4; ti++){
      int row = w*32 + ti*8 + rIn;
      gload16(Q + ((int64_t)sb*LSEQ + q0 + row)*DM + h*DHD + d16*8, &As[(w*32+ti*8)*64]);
      gload16(K + ((int64_t)sb*LSEQ + k0t + row)*DM + h*DHD + d16*8, &Bs[(w*32+ti*8)*64]);
    }
    __syncthreads();
    #pragma unroll
    for(int kk=0;kk<2;kk++){
      int p = (kk*4+quad) ^ (lane&7);
      bf16x8 af[4], bfv[4];
      #pragma unroll
      for(int i=0;i<4;i++) af[i]  = *(const bf16x8*)&As[(mw+i*16+ln15)*64 + p*8];
      #pragma unroll
      for(int j=0;j<4;j++) bfv[j] = *(const bf16x8*)&Bs[(nw+j*16+ln15)*64 + p*8];
      #pragma unroll
      for(int i=0;i<4;i++)
        #pragma unroll
        for(int j=0;j<4;j++)
          acc[i][j] = __builtin_amdgcn_mfma_f32_16x16x32_bf16(af[i], bfv[j], acc[i][j], 0,0,0);
    }
  }
  int64_t slab = (int64_t)sc*NH*LL;
  #pragma unroll
  for(int i=0;i<4;i++)
    #pragma unroll
    for(int reg=0;reg<4;reg++){
      int q = q0 + mw + i*16 + quad*4 + reg;
      float* rp = scores + slab + ((int64_t)h*LSEQ + q)*LSEQ + k0t + nw + ln15;
      #pragma unroll
      for(int j=0;j<4;j++) rp[j*16] = acc[i][j][reg];
    }
}

// ---------------- K8: sum slabs + bias, softmax over k -> P bf16 -----------
__global__ __launch_bounds__(128) void k_softmax(const float* __restrict__ scores,
    const float* __restrict__ bias, u16* __restrict__ Pb){
  int hq = blockIdx.x, t = threadIdx.x;
  int64_t base = (int64_t)hq*LSEQ;
  float v[3];
  #pragma unroll
  for(int i=0;i<3;i++){
    int k = t + i*128;
    float x = bias[base+k];
    x += scores[base+k];
    x += scores[(int64_t)1*NH*LL + base + k];
    x += scores[(int64_t)2*NH*LL + base + k];
    x += scores[(int64_t)3*NH*LL + base + k];
    v[i]=x;
  }
  __shared__ float red[2], red2[2];
  int wv=t>>6, ln=t&63;
  float m = fmaxf(fmaxf(v[0],v[1]),v[2]);
  m = wmax(m);
  if(ln==0) red[wv]=m;
  __syncthreads();
  m = fmaxf(red[0],red[1]);
  float e = __expf(v[0]-m)+__expf(v[1]-m)+__expf(v[2]-m);
  e = wsum(e);
  if(ln==0) red2[wv]=e;
  __syncthreads();
  float inv = 1.f/(red2[0]+red2[1]);
  #pragma unroll
  for(int i=0;i<3;i++) Pb[base + t + i*128] = f2b(__expf(v[i]-m)*inv);
}

// ---------------- K9: PV. C[(s,d)][q] = sum_k VT[h][(s,d)][k] * P[h][q][k] --
__global__ __launch_bounds__(256) void k_pv(const u16* __restrict__ VT,
    const u16* __restrict__ Pb, const u16* __restrict__ gbuf,
    u16* __restrict__ attn){
  __shared__ short As[128*64];
  __shared__ short Bs[128*64];
  int t = threadIdx.x;
  int w = t>>6, lane = t&63, ln15 = lane&15, quad = lane>>4;
  int rIn = lane>>3, cch = lane&7;
  int mw = (w>>1)*64, nw = (w&1)*64;
  int mx = blockIdx.x, ny = blockIdx.y, h = blockIdx.z;
  int g = cch ^ rIn;
  f32x4 acc[4][4] = {};
  for(int it=0; it<6; it++){
    int k0 = it*64;
    __syncthreads();
    #pragma unroll
    for(int ti=0; ti<4; ti++){
      int row = w*32 + ti*8 + rIn;
      gload16(VT + ((int64_t)h*8192 + mx*128 + row)*LSEQ + k0 + g*8, &As[(w*32+ti*8)*64]);
      gload16(Pb + ((int64_t)h*LSEQ + ny*128 + row)*LSEQ + k0 + g*8, &Bs[(w*32+ti*8)*64]);
    }
    __syncthreads();
    #pragma unroll
    for(int kk=0;kk<2;kk++){
      int p = (kk*4+quad) ^ (lane&7);
      bf16x8 af[4], bfv[4];
      #pragma unroll
      for(int i=0;i<4;i++) af[i]  = *(const bf16x8*)&As[(mw+i*16+ln15)*64 + p*8];
      #pragma unroll
      for(int j=0;j<4;j++) bfv[j] = *(const bf16x8*)&Bs[(nw+j*16+ln15)*64 + p*8];
      #pragma unroll
      for(int i=0;i<4;i++)
        #pragma unroll
        for(int j=0;j<4;j++)
          acc[i][j] = __builtin_amdgcn_mfma_f32_16x16x32_bf16(af[i], bfv[j], acc[i][j], 0,0,0);
    }
  }
  #pragma unroll
  for(int i=0;i<4;i++){
    int m0 = mx*128 + mw + i*16 + quad*4;
    int s = m0>>5, d0 = m0&31;
    #pragma unroll
    for(int j=0;j<4;j++){
      int q = ny*128 + nw + j*16 + ln15;
      int64_t base = ((int64_t)s*LSEQ + q)*DM + h*DHD + d0;
      ushort4 gv = *(const ushort4*)(gbuf + base);
      ushort4 o;
      o.x = f2b(acc[i][j][0]*b2f(gv.x));
      o.y = f2b(acc[i][j][1]*b2f(gv.y));
      o.z = f2b(acc[i][j][2]*b2f(gv.z));
      o.w = f2b(acc[i][j][3]*b2f(gv.w));
      *(ushort4*)(attn + base) = o;
    }
  }
}

// ---------------- K10: out = attnout @ wo + bo (fp32 out) ------------------
__global__ __launch_bounds__(256) void k_final(const u16* __restrict__ A,
    const u16* __restrict__ WOT, const float* __restrict__ bo,
    float* __restrict__ out){
  __shared__ short As[128*64];
  __shared__ short Bs[128*64];
  int t = threadIdx.x;
  int w = t>>6, lane = t&63, ln15 = lane&15, quad = lane>>4;
  int rIn = lane>>3, cch = lane&7;
  int mw = (w>>1)*64, nw = (w&1)*64;
  int n0 = blockIdx.x*128;
  int64_t r0 = (int64_t)blockIdx.y*128;
  int g = cch ^ rIn;
  f32x4 acc[4][4] = {};
  for(int it=0; it<4; it++){
    int k0 = it*64;
    __syncthreads();
    #pragma unroll
    for(int ti=0; ti<4; ti++){
      int row = w*32 + ti*8 + rIn;
      gload16(A   + (r0+row)*DM + k0 + g*8, &As[(w*32+ti*8)*64]);
      gload16(WOT + (int64_t)(n0+row)*DM + k0 + g*8, &Bs[(w*32+ti*8)*64]);
    }
    __syncthreads();
    #pragma unroll
    for(int kk=0;kk<2;kk++){
      int p = (kk*4+quad) ^ (lane&7);
      bf16x8 af[4], bfv[4];
      #pragma unroll
      for(int i=0;i<4;i++) af[i]  = *(const bf16x8*)&As[(mw+i*16+ln15)*64 + p*8];
      #pragma unroll
      for(int j=0;j<4;j++) bfv[j] = *(const bf16x8*)&Bs[(nw+j*16+ln15)*64 + p*8];
      #pragma unroll
      for(int i=0;i<4;i++)
        #pragma unroll
        for(int j=0;j<4;j++)
          acc[i][j] = __builtin_amdgcn_mfma_f32_16x16x32_bf16(af[i], bfv[j], acc[i][j], 0,0,0);
    }
  }
  float bv[4];
  #pragma unroll
  for(int j=0;j<4;j++) bv[j] = bo[n0 + nw + j*16 + ln15];
  #pragma unroll
  for(int i=0;i<4;i++)
    #pragma unroll
    for(int reg=0;reg<4;reg++){
      int64_t r = r0 + mw + i*16 + quad*4 + reg;
      float* rp = out + r*DM + n0 + nw + ln15;
      #pragma unroll
      for(int j=0;j<4;j++) rp[j*16] = acc[i][j][reg] + bv[j];
    }
}

extern "C" void kernel_launch(void* const* d_in, const int* in_sizes, int n_in,
                              void* d_out, int out_size, void* d_ws, size_t ws_size,
                              hipStream_t stream){
  const float* msa    = (const float*)d_in[0];
  const float* pair   = (const float*)d_in[1];
  const float* lmg    = (const float*)d_in[2];
  const float* lmb    = (const float*)d_in[3];
  const float* lpg    = (const float*)d_in[4];
  const float* lpb    = (const float*)d_in[5];
  const float* sw_q_w = (const float*)d_in[6];
  const float* sw_q_b = (const float*)d_in[7];
  const float* sw_k_w = (const float*)d_in[8];
  // d_in[9] = sw_k_b: constant over n, cancels in softmax over n.
  const float* wq     = (const float*)d_in[10];
  const float* wk     = (const float*)d_in[11];
  const float* wv     = (const float*)d_in[12];
  const float* wb     = (const float*)d_in[13];
  const float* wg     = (const float*)d_in[14];
  const float* bg     = (const float*)d_in[15];
  const float* wo     = (const float*)d_in[16];
  const float* bo     = (const float*)d_in[17];
  float* out = (float*)d_out;

  // workspace layout (~285 MB)
  u16* msa_n = (u16*)d_ws;                       // [NL][256] bf16
  u16* qb    = msa_n + (int64_t)NL*DM;
  u16* kb    = qb + (int64_t)NL*DM;
  u16* gbuf  = kb + (int64_t)NL*DM;
  u16* VT    = gbuf + (int64_t)NL*DM;            // [8][256][32][384] bf16
  u16* Pb    = VT + (int64_t)NL*DM;              // [8][384][384] bf16
  u16* WTall = Pb + (int64_t)NH*LSEQ*LSEQ;       // [1024][256] bf16
  u16* WOT   = WTall + 1024*DM;                  // [256][256] bf16
  float* u_buf = (float*)(WOT + DM*DM);          // [384][8][256] f32
  float* sw  = u_buf + (int64_t)LSEQ*NH*DM;      // [256*384][8] f32
  float* bias = sw + (int64_t)NL*NH;             // [8][384][384] f32
  float* scores = bias + (int64_t)NH*LL;         // 4 slabs [8][384][384] f32
  u16* attnout = msa_n;                          // alias: msa_n dead after proj

  k_ln_msa<<<NL/4, 256, 0, stream>>>(msa, lmg, lmb, msa_n);
  k_wconv<<<dim3(4,4,5), 256, 0, stream>>>(wq, wk, wv, wg, wo, WTall, WOT);
  k_u<<<LSEQ, 256, 0, stream>>>(msa_n, sw_q_w, sw_q_b, sw_k_w, u_buf);
  k_seqw<<<LSEQ, 256, 0, stream>>>(msa_n, u_buf, sw);
  k_bias<<<LL/256, 256, 0, stream>>>(pair, lpg, lpb, wb, bias);
  k_projf<<<dim3(NL/128), 256, 0, stream>>>(msa_n, WTall, qb, kb, gbuf, VT, sw, bg);
  k_scores<<<dim3(3,3,32), 256, 0, stream>>>(qb, kb, scores);
  k_softmax<<<NH*LSEQ, 128, 0, stream>>>(scores, bias, Pb);
  k_pv<<<dim3(64,3,NH), 256, 0, stream>>>(VT, Pb, gbuf, attnout);
  k_final<<<dim3(2, NL/128), 256, 0, stream>>>(attnout, WOT, bo, out);
}